// Round 5
// baseline (145.721 us; speedup 1.0000x reference)
//
#include <hip/hip_runtime.h>

// GIoU loss, N=4M boxes, [N,4] f32 -> one float4 per box (16B/lane coalesced).
// 128 MB read/call.
// R2-R4: pinned at 42.5us = 3.0 TB/s via the IF$-retention read path.
// R6: nontemporal loads -> main ~34us by subtraction. Fill shows 6.6 TB/s.
// R7: __launch_bounds__(256,4), 16-load batch -> 135.5us. BEST so far.
// R8: 32 waves/CU -> null. Occupancy/capacity is not the limiter.
// R9: cooperative fuse -> 255us (grid-sync spin cross-XCD). Never again.
// R10: last-block fuse -> 120us kernel (1954 cross-XCD atomic tickets
//      serialize retirement). Two-kernel split is mandatory. Datum:
//      FETCH=64MB of 128MB -> half the input L3-resident.
// R11: sched_barrier batch pin -> null (135.3).
// R12 (this round): duty-cycle theory. BDP is only ~17KB/CU, so BW is
//      saturated WHENEVER loads are outstanding; 3.8/6.3 = 0.60 equals the
//      estimated fraction of block lifetime with loads in flight. The loss
//      is the zero-outstanding window per block (tail compute + reduce +
//      retire + relaunch + prologue). Fix: single resident block-wave
//      (grid=489, CHUNK=8192, launch_bounds(256,2), zero churn) + depth-3
//      register pipeline (batches of 8 pairs; b+1,b+2 in flight while
//      computing b; sched_barrier(0) pins each stage). Predict main ~34 ->
//      ~22us, dur_us -> ~122-126. If null: declare roofline (harness floor).

#define TPB     256
#define PAIRS   32                  // (p,t) pairs per thread
#define BATCH   8                   // pairs per pipeline stage
#define NBATCH  (PAIRS / BATCH)     // 4 stages
#define CHUNK   (TPB * PAIRS)       // 8192 boxes per block

typedef float vfloat4 __attribute__((ext_vector_type(4)));

__device__ __forceinline__ vfloat4 nt_load(const vfloat4* p) {
    return __builtin_nontemporal_load(p);
}

__device__ __forceinline__ float giou_term(vfloat4 p, vfloat4 t) {
    // box = {x1,y1,x2,y2}
    float area_p = (p.z - p.x) * (p.w - p.y);
    float area_t = (t.z - t.x) * (t.w - t.y);
    float iw = fmaxf(fminf(p.z, t.z) - fmaxf(p.x, t.x), 0.0f);
    float ih = fmaxf(fminf(p.w, t.w) - fmaxf(p.y, t.y), 0.0f);
    float inter = iw * ih;
    float uni   = area_p + area_t - inter;
    float iou   = inter / uni;
    float cw = fmaxf(p.z, t.z) - fminf(p.x, t.x);
    float ch = fmaxf(p.w, t.w) - fminf(p.y, t.y);
    float area_c = cw * ch;
    return 1.0f - (iou - (area_c - uni) / area_c);
}

// Load stage b (8 interleaved p,t pairs = 16 nt dwordx4), compute stage b.
// All loop trips are constant -> fully unrolled, all indices compile-time
// (rule: runtime-indexed ext_vector arrays go to scratch).
#define LOAD_BATCH(b)                                                       \
    _Pragma("unroll")                                                       \
    for (int k = 0; k < BATCH; ++k) {                                       \
        p[b][k] = nt_load(&pred[i0 + ((b) * BATCH + k) * TPB]);             \
        t[b][k] = nt_load(&targ[i0 + ((b) * BATCH + k) * TPB]);             \
    }

#define COMP_BATCH(b)                                                       \
    _Pragma("unroll")                                                       \
    for (int k = 0; k < BATCH; ++k) sum += giou_term(p[b][k], t[b][k]);

__global__ __launch_bounds__(TPB, 2) void giou_main_kernel(
        const vfloat4* __restrict__ pred,
        const vfloat4* __restrict__ targ,
        float* __restrict__ partials,
        int n) {
    const int base = blockIdx.x * CHUNK;
    const int i0   = base + threadIdx.x;
    float sum = 0.0f;

    if (base + CHUNK <= n) {
        vfloat4 p[NBATCH][BATCH], t[NBATCH][BATCH];
        // Depth-3 pipeline: while stage b is consumed, stages b+1 and b+2
        // are in flight. sched_barrier(0) forbids the allocator from
        // sinking a load stage below the following compute (that is what
        // silently produced the 36-VGPR MLP~2 code in R10).
        LOAD_BATCH(0)
        LOAD_BATCH(1)
        __builtin_amdgcn_sched_barrier(0);
        LOAD_BATCH(2)
        __builtin_amdgcn_sched_barrier(0);
        COMP_BATCH(0)
        LOAD_BATCH(3)
        __builtin_amdgcn_sched_barrier(0);
        COMP_BATCH(1)
        COMP_BATCH(2)
        COMP_BATCH(3)
    } else {
        // tail block (only the last one): guarded scalar path
        for (int k = 0; k < PAIRS; ++k) {
            int i = i0 + k * TPB;
            if (i < n) sum += giou_term(nt_load(&pred[i]), nt_load(&targ[i]));
        }
    }

    // wave reduce (wave = 64)
    #pragma unroll
    for (int off = 32; off > 0; off >>= 1)
        sum += __shfl_down(sum, off, 64);

    __shared__ float wave_sums[TPB / 64];
    const int lane = threadIdx.x & 63;
    const int wid  = threadIdx.x >> 6;
    if (lane == 0) wave_sums[wid] = sum;
    __syncthreads();
    if (threadIdx.x == 0) {
        partials[blockIdx.x] = wave_sums[0] + wave_sums[1]
                             + wave_sums[2] + wave_sums[3];
    }
}

__global__ __launch_bounds__(TPB) void giou_finalize_kernel(
        const float* __restrict__ partials, int nblocks,
        float* __restrict__ out, double inv_n) {
    double s = 0.0;
    for (int i = threadIdx.x; i < nblocks; i += TPB)
        s += (double)partials[i];
    #pragma unroll
    for (int off = 32; off > 0; off >>= 1)
        s += __shfl_down(s, off, 64);
    __shared__ double wave_sums[TPB / 64];
    int lane = threadIdx.x & 63;
    int wid  = threadIdx.x >> 6;
    if (lane == 0) wave_sums[wid] = s;
    __syncthreads();
    if (threadIdx.x == 0) {
        double tot = wave_sums[0] + wave_sums[1] + wave_sums[2] + wave_sums[3];
        *out = (float)(tot * inv_n);
    }
}

extern "C" void kernel_launch(void* const* d_in, const int* in_sizes, int n_in,
                              void* d_out, int out_size, void* d_ws, size_t ws_size,
                              hipStream_t stream) {
    const vfloat4* pred = (const vfloat4*)d_in[0];
    const vfloat4* targ = (const vfloat4*)d_in[1];
    float* out      = (float*)d_out;
    float* partials = (float*)d_ws;          // nblocks floats, all written
    int n = in_sizes[0] / 4;                 // 4,000,000 boxes
    int nblocks = (n + CHUNK - 1) / CHUNK;   // 489 -> single resident wave

    giou_main_kernel<<<nblocks, TPB, 0, stream>>>(pred, targ, partials, n);
    giou_finalize_kernel<<<1, TPB, 0, stream>>>(partials, nblocks, out,
                                                1.0 / (double)n);
}

// Round 6
// 137.342 us; speedup vs baseline: 1.0610x; 1.0610x over previous
//
#include <hip/hip_runtime.h>

// GIoU loss, N=4M boxes, [N,4] f32 -> one float4 per box (16B/lane coalesced).
// 128 MB read/call.
// R2-R4: pinned at 42.5us = 3.0 TB/s via the IF$-retention read path.
// R6: nontemporal loads -> main ~34us by subtraction. Fill shows 6.6 TB/s.
// R7: __launch_bounds__(256,4), 16-load batch -> 135.5us. BEST so far.
// R8: 32 waves/CU -> null. Capacity is not the limiter.
// R9: cooperative fuse -> 255us (grid-sync spin cross-XCD). Never again.
// R10: last-block fuse -> 120us kernel (cross-XCD ticket serializes
//      retirement). Two-kernel split mandatory. FETCH=64MB of 128MB: half
//      the input is L3-resident across iterations.
// R11: sched_barrier batch pin -> null. Within-block pinning is the wrong
//      boundary; the drain is at block turnover.
// R12: depth-3 pipeline REGRESSED (145.7) -- p[4][8]+t[4][8]=256 data VGPRs
//      vs 256 cap = guaranteed scratch spill. Theory untested. Lesson: size
//      the live set against the cap BEFORE shipping.
// R13 (this round): clean duty-cycle test. Persistent 512-block grid
//      (2/CU, all resident, zero block churn), named-buffer double-buffer
//      BATCH=6 (96 data VGPRs, ~130 total, no spill), sched_barrier(0)
//      after each prefetch issue. Loads outstanding prologue->epilogue.
//      Predict main ~34 -> ~22us, dur_us -> ~122-127.
//      PRE-COMMITTED: dur_us in [133,138] => duty-cycle falsified =>
//      declare ROOFLINE next round.

#define TPB    256
#define GRID   512                  // 2 blocks/CU on 256 CUs, all resident
#define BATCH  6                    // pairs per buffer; 2 buffers live

typedef float vfloat4 __attribute__((ext_vector_type(4)));

__device__ __forceinline__ vfloat4 nt_load(const vfloat4* p) {
    return __builtin_nontemporal_load(p);
}

__device__ __forceinline__ float giou_term(vfloat4 p, vfloat4 t) {
    // box = {x1,y1,x2,y2}
    float area_p = (p.z - p.x) * (p.w - p.y);
    float area_t = (t.z - t.x) * (t.w - t.y);
    float iw = fmaxf(fminf(p.z, t.z) - fmaxf(p.x, t.x), 0.0f);
    float ih = fmaxf(fminf(p.w, t.w) - fmaxf(p.y, t.y), 0.0f);
    float inter = iw * ih;
    float uni   = area_p + area_t - inter;
    float iou   = inter / uni;
    float cw = fmaxf(p.z, t.z) - fminf(p.x, t.x);
    float ch = fmaxf(p.w, t.w) - fminf(p.y, t.y);
    float area_c = cw * ch;
    return 1.0f - (iou - (area_c - uni) / area_c);
}

// Named-buffer load/compute stages. Array indices are compile-time (k);
// the pair index m is runtime (fine -- it only feeds address arithmetic).
#define LOAD(P, T, mbase)                                                   \
    do {                                                                    \
        _Pragma("unroll")                                                   \
        for (int k = 0; k < BATCH; ++k) {                                   \
            P[k] = nt_load(&pred[tid0 + ((mbase) + k) * S]);                \
            T[k] = nt_load(&targ[tid0 + ((mbase) + k) * S]);                \
        }                                                                   \
    } while (0)

#define COMP(P, T)                                                          \
    do {                                                                    \
        _Pragma("unroll")                                                   \
        for (int k = 0; k < BATCH; ++k) sum += giou_term(P[k], T[k]);       \
    } while (0)

__global__ __launch_bounds__(TPB, 2) void giou_main_kernel(
        const vfloat4* __restrict__ pred,
        const vfloat4* __restrict__ targ,
        float* __restrict__ partials,
        int n) {
    const int S    = GRID * TPB;                       // stride: 131072
    const int tid0 = blockIdx.x * TPB + threadIdx.x;
    float sum = 0.0f;

    const int nfull = n / S;            // unguarded strided pairs (30 @ N=4M)
    const int nb    = nfull / BATCH;    // full batches (5)

    vfloat4 pA[BATCH], tA[BATCH], pB[BATCH], tB[BATCH];

    int m = 0;
    if (nb > 0) {
        LOAD(pA, tA, m);                       // prologue: A in flight
        int done = 1;
        while (done + 1 < nb) {                // two batches per iteration
            LOAD(pB, tB, m + BATCH);           // prefetch B
            __builtin_amdgcn_sched_barrier(0); // B stays above compute A
            COMP(pA, tA);  m += BATCH;
            LOAD(pA, tA, m + BATCH);           // prefetch A
            __builtin_amdgcn_sched_barrier(0);
            COMP(pB, tB);  m += BATCH;
            done += 2;
        }
        if (done < nb) {                       // even nb: one load left
            LOAD(pB, tB, m + BATCH);
            __builtin_amdgcn_sched_barrier(0);
            COMP(pA, tA);  m += BATCH;
            COMP(pB, tB);  m += BATCH;
        } else {                               // odd nb: drain A
            COMP(pA, tA);  m += BATCH;
        }
    }
    // leftover unguarded pairs (nfull % BATCH, = 0 at N=4M)
    for (; m < nfull; ++m)
        sum += giou_term(nt_load(&pred[tid0 + m * S]),
                         nt_load(&targ[tid0 + m * S]));
    // guarded tail (last partial stride)
    for (int i = tid0 + m * S; i < n; i += S)
        sum += giou_term(nt_load(&pred[i]), nt_load(&targ[i]));

    // wave reduce (wave = 64)
    #pragma unroll
    for (int off = 32; off > 0; off >>= 1)
        sum += __shfl_down(sum, off, 64);

    __shared__ float wave_sums[TPB / 64];
    const int lane = threadIdx.x & 63;
    const int wid  = threadIdx.x >> 6;
    if (lane == 0) wave_sums[wid] = sum;
    __syncthreads();
    if (threadIdx.x == 0) {
        partials[blockIdx.x] = wave_sums[0] + wave_sums[1]
                             + wave_sums[2] + wave_sums[3];
    }
}

__global__ __launch_bounds__(TPB) void giou_finalize_kernel(
        const float* __restrict__ partials, int nblocks,
        float* __restrict__ out, double inv_n) {
    double s = 0.0;
    for (int i = threadIdx.x; i < nblocks; i += TPB)
        s += (double)partials[i];
    #pragma unroll
    for (int off = 32; off > 0; off >>= 1)
        s += __shfl_down(s, off, 64);
    __shared__ double wave_sums[TPB / 64];
    int lane = threadIdx.x & 63;
    int wid  = threadIdx.x >> 6;
    if (lane == 0) wave_sums[wid] = s;
    __syncthreads();
    if (threadIdx.x == 0) {
        double tot = wave_sums[0] + wave_sums[1] + wave_sums[2] + wave_sums[3];
        *out = (float)(tot * inv_n);
    }
}

extern "C" void kernel_launch(void* const* d_in, const int* in_sizes, int n_in,
                              void* d_out, int out_size, void* d_ws, size_t ws_size,
                              hipStream_t stream) {
    const vfloat4* pred = (const vfloat4*)d_in[0];
    const vfloat4* targ = (const vfloat4*)d_in[1];
    float* out      = (float*)d_out;
    float* partials = (float*)d_ws;          // GRID floats, all written
    int n = in_sizes[0] / 4;                 // 4,000,000 boxes

    giou_main_kernel<<<GRID, TPB, 0, stream>>>(pred, targ, partials, n);
    giou_finalize_kernel<<<1, TPB, 0, stream>>>(partials, GRID, out,
                                                1.0 / (double)n);
}